// Round 7
// baseline (878.050 us; speedup 1.0000x reference)
//
#include <hip/hip_runtime.h>
#include <math.h>

#define BATCH 4
#define NN 4096
#define DIN 128
#define DE 64
#define KK 16
#define CHUNK 128   // cols per chunk in kernel 2 (lane owns cols lane, lane+64)
#define GATEF 1e-3f

// ---------------- Kernel 1: xe = x @ W + bias, golden-replica f32 ----------------
// BLAS-backend replica: per output element, acc = fma(x[d], W[d,e], acc),
// d = 0..127 ascending from 0, then + bias (separate f32 add).
__global__ __launch_bounds__(256) void embed_kernel(
    const float* __restrict__ x, const float* __restrict__ W,
    const float* __restrict__ bias, float* __restrict__ xe) {
#pragma clang fp contract(off)
  __shared__ float wl[DIN][DE];   // 32 KB
  __shared__ float xs[4][DIN];    // 2 KB
  int t = threadIdx.x;
  for (int i = t * 4; i < DIN * DE; i += 1024)
    *(float4*)&wl[i >> 6][i & 63] = *(const float4*)&W[i];
  {
    int rr = t >> 6, dd = (t & 63) * 2;
    const float* src = x + ((size_t)blockIdx.x * 4 + rr) * DIN + dd;
    xs[rr][dd] = src[0];
    xs[rr][dd + 1] = src[1];
  }
  __syncthreads();
  int w = t >> 6, lane = t & 63;
  float acc = 0.f;
#pragma unroll
  for (int d = 0; d < DIN; ++d)
    acc = __builtin_fmaf(xs[w][d], wl[d][lane], acc);  // sequential FMA chain
  xe[((size_t)blockIdx.x * 4 + w) * DE + lane] = acc + bias[lane];
}

// numpy pairwise sum (n=64, scalar 8-accumulator path) of squares of a
// 64-float row. Squares are f32-rounded by the mul (numpy: xe*xe temp),
// sums are plain f32 adds in numpy's exact order.
template <int STRIDE>
__device__ inline float np_pairwise_sq64(const float* a) {
#pragma clang fp contract(off)
  float p[8];
#pragma unroll
  for (int j = 0; j < 8; ++j) {
    float v = a[j * STRIDE];
    p[j] = v * v;
  }
#pragma unroll
  for (int i = 8; i < 64; i += 8) {
#pragma unroll
    for (int j = 0; j < 8; ++j) {
      float v = a[(i + j) * STRIDE];
      p[j] = p[j] + v * v;
    }
  }
  return ((p[0] + p[1]) + (p[2] + p[3])) + ((p[4] + p[5]) + (p[6] + p[7]));
}

// Screen G: device logf (<=1-2 ulp) — only gates the exact eval.
__device__ inline float gumbel_G_screen(float qv) {
  float t1 = qv + 1e-8f;
  return logf(-logf(t1));
}
// Exact G: correctly-rounded f32 logs via f64 log + round.
__device__ inline float gumbel_G_exact(float qv) {
  float t1 = qv + 1e-8f;
  float l1 = (float)log((double)t1);
  float l2 = -l1;
  return (float)log((double)l2);
}

// ---------------- Kernel 2: f32 golden-replica distances + Gumbel top-K ----------------
// gram: sequential FMA over d (BLAS micro-kernel order).
// sq:   numpy pairwise 8-accumulator order (both row and column norms).
__global__ __launch_bounds__(256) void dgm_topk_kernel(
    const float* __restrict__ xe, const float* __restrict__ q,
    const float* __restrict__ temp, float* __restrict__ e0,
    float* __restrict__ e1, float* __restrict__ lp) {
#pragma clang fp contract(off)
  __shared__ float ct[CHUNK][DE + 4];  // 128 x 68 f32 = 34.8 KB
  __shared__ float rt[32][DE + 4];     // 8.7 KB
  __shared__ float topv_s[32][KK];     // sorted ascending f32 lq
  __shared__ int topi_s[32][KK];

  int t = threadIdx.x;
  int w = __builtin_amdgcn_readfirstlane(t >> 6);
  int lane = t & 63;
  int bb = (int)blockIdx.x >> 7;
  int row0 = ((int)blockIdx.x & 127) * 32;
  const float* xb = xe + (size_t)bb * NN * DE;

  for (int i = t; i < 32 * KK; i += 256) {
    ((float*)topv_s)[i] = __builtin_inff();
    ((int*)topi_s)[i] = 0;
  }

  {  // stage row tile: thread -> row t>>3, dims (t&7)*8 .. +7
    int rr = t >> 3, d0 = (t & 7) * 8;
    const float* src = xb + (size_t)(row0 + rr) * DE + d0;
    *(float4*)&rt[rr][d0] = ((const float4*)src)[0];
    *(float4*)&rt[rr][d0 + 4] = ((const float4*)src)[1];
  }
  __syncthreads();

  // row sq-norms: numpy pairwise order (wave-uniform broadcast reads)
  float sqr[8];
#pragma unroll
  for (int r = 0; r < 8; ++r) sqr[r] = np_pairwise_sq64<1>(&rt[w * 8 + r][0]);

  // scale: correctly-rounded f32 exp of clipped temperature
  double tc = (double)temp[0];
  float s32 = (float)exp(fmin(fmax(tc, -5.0), 5.0));

  int rb = row0 + w * 8;
  const float* qbase = q + ((size_t)bb * NN + rb) * NN;

  for (int c0 = 0; c0 < NN; c0 += CHUNK) {
    __syncthreads();  // previous chunk's ct reads done
    {                 // stage ct: flat copy of 128 contiguous xe rows
      const float* src = xb + (size_t)c0 * DE;
#pragma unroll
      for (int j = 0; j < 8; ++j) {
        int idx = (j * 256 + t) * 4;  // float index in [0, 8192)
        float4 v = *(const float4*)&src[idx];
        *(float4*)&ct[idx >> 6][idx & 63] = v;
      }
    }
    __syncthreads();  // ct ready

    // column sq-norms (this lane's 2 cols): numpy pairwise order
    float sqc0 = np_pairwise_sq64<1>(&ct[lane][0]);
    float sqc1 = np_pairwise_sq64<1>(&ct[lane + 64][0]);

    // gram: sequential FMA over d (BLAS micro-kernel order)
    float acc0[8] = {0, 0, 0, 0, 0, 0, 0, 0};
    float acc1[8] = {0, 0, 0, 0, 0, 0, 0, 0};
#pragma unroll
    for (int dd = 0; dd < DE; dd += 4) {
      float4 b0 = *(const float4*)&ct[lane][dd];
      float4 b1 = *(const float4*)&ct[lane + 64][dd];
#pragma unroll
      for (int r = 0; r < 8; ++r) {
        float4 a = *(const float4*)&rt[w * 8 + r][dd];  // broadcast
        float t0 = acc0[r], t1 = acc1[r];
        t0 = __builtin_fmaf(a.x, b0.x, t0);
        t0 = __builtin_fmaf(a.y, b0.y, t0);
        t0 = __builtin_fmaf(a.z, b0.z, t0);
        t0 = __builtin_fmaf(a.w, b0.w, t0);
        t1 = __builtin_fmaf(a.x, b1.x, t1);
        t1 = __builtin_fmaf(a.y, b1.y, t1);
        t1 = __builtin_fmaf(a.z, b1.z, t1);
        t1 = __builtin_fmaf(a.w, b1.w, t1);
        acc0[r] = t0;
        acc1[r] = t1;
      }
    }

    float D0[8], D1[8], ap0[8], ap1[8];
    float qv0[8], qv1[8];
#pragma unroll
    for (int r = 0; r < 8; ++r) {
      qv0[r] = qbase[(size_t)r * NN + c0 + lane];
      qv1[r] = qbase[(size_t)r * NN + c0 + 64 + lane];
      // D = max((sq_n + sq_m) - 2*gram, 0), discrete f32 ops in ref order
      float u0 = (sqr[r] + sqc0) - 2.0f * acc0[r];
      float u1 = (sqr[r] + sqc1) - 2.0f * acc1[r];
      D0[r] = fmaxf(u0, 0.0f);
      D1[r] = fmaxf(u1, 0.0f);
      ap0[r] = D0[r] * s32 - gumbel_G_screen(qv0[r]);
      ap1[r] = D1[r] * s32 - gumbel_G_screen(qv1[r]);
    }

    // gated exact eval + streaming top-16 (smallest f32 lq), stable ties
    for (int r = 0; r < 8; ++r) {
      int rl = w * 8 + r;
      float thr = topv_s[rl][KK - 1];
      bool g0 = ap0[r] < thr + GATEF;
      bool g1 = ap1[r] < thr + GATEF;
      if (!__ballot(g0 || g1)) continue;
      float v0 = g0 ? D0[r] * s32 - gumbel_G_exact(qv0[r]) : __builtin_inff();
      float v1 = g1 ? D1[r] * s32 - gumbel_G_exact(qv1[r]) : __builtin_inff();
      bool a0 = g0, a1 = g1;
      while (true) {
        float m0 = a0 ? v0 : __builtin_inff();
        float m1 = a1 ? v1 : __builtin_inff();
        float vm = fminf(m0, m1);
#pragma unroll
        for (int off = 32; off > 0; off >>= 1)
          vm = fminf(vm, __shfl_xor(vm, off));
        if (vm >= thr) break;  // uniform
        unsigned long long em0 = __ballot(a0 && (v0 == vm));
        int src, col;
        bool s1;
        if (em0) {  // slot0 cols all lower than slot1 cols
          src = __builtin_ctzll(em0);
          col = c0 + src;
          s1 = false;
        } else {
          unsigned long long em1 = __ballot(a1 && (v1 == vm));
          src = __builtin_ctzll(em1);
          col = c0 + 64 + src;
          s1 = true;
        }
        float tv = __builtin_inff();
        int ti = 0;
        if (lane < KK) {
          tv = topv_s[rl][lane];
          ti = topi_s[rl][lane];
        }
        int pos = __builtin_popcountll(__ballot((lane < KK) && (tv <= vm)));
        float tvu = __shfl_up(tv, 1);
        int tiu = __shfl_up(ti, 1);
        float nv = (lane == pos) ? vm : ((lane > pos) ? tvu : tv);
        int ni = (lane == pos) ? col : ((lane > pos) ? tiu : ti);
        if (lane < KK) {
          topv_s[rl][lane] = nv;
          topi_s[rl][lane] = ni;
        }
        thr = __shfl(nv, KK - 1);
        if (lane == src) {
          if (s1) a1 = false; else a0 = false;
        }
      }
    }
  }

  // outputs
#pragma unroll
  for (int r = 0; r < 8; ++r) {
    int rl = w * 8 + r;
    int n = row0 + rl;
    if (lane < KK) {
      size_t o = ((size_t)bb * NN + n) * KK + lane;
      lp[o] = -topv_s[rl][lane];
      e0[o] = (float)(topi_s[rl][lane] + bb * NN);
      e1[o] = (float)(n + bb * NN);
    }
  }
}

extern "C" void kernel_launch(void* const* d_in, const int* in_sizes, int n_in,
                              void* d_out, int out_size, void* d_ws,
                              size_t ws_size, hipStream_t stream) {
  (void)in_sizes; (void)n_in; (void)d_ws; (void)ws_size; (void)out_size;
  const float* x = (const float*)d_in[0];
  // d_in[1] = A (unused placeholder)
  const float* W = (const float*)d_in[2];
  const float* bias = (const float*)d_in[3];
  const float* temp = (const float*)d_in[4];
  const float* q = (const float*)d_in[5];

  float* xe = (float*)d_out;                 // [4,4096,64] f32 (also k2 input)
  float* e0 = xe + (size_t)BATCH * NN * DE;  // edges row 0 (indices)
  float* e1 = e0 + (size_t)BATCH * NN * KK;  // edges row 1 (rows)
  float* lp = e1 + (size_t)BATCH * NN * KK;  // logprobs

  embed_kernel<<<BATCH * NN / 4, 256, 0, stream>>>(x, W, bias, xe);
  dgm_topk_kernel<<<BATCH * 128, 256, 0, stream>>>(xe, q, temp, e0, e1, lp);
}